// Round 17
// baseline (210.881 us; speedup 1.0000x reference)
//
#include <hip/hip_runtime.h>

#define NN 8000
#define FD 256
#define NEG_SLOPE 0.2f
#define BM 64                 // i rows per block
#define KT 32                 // j per step
#define JCH 2048              // j chunk (last: 1856)

typedef __bf16 bf16;
typedef __bf16 bf16x8 __attribute__((ext_vector_type(8)));
typedef __bf16 bf16x4 __attribute__((ext_vector_type(4)));
typedef float f32x4 __attribute__((ext_vector_type(4)));

// ---------------- K1: H = X @ W^T + b -> Ht (bf16, [f][i]); zero out/lg ----
__global__ __launch_bounds__(256) void k_linear(const float* __restrict__ X,
                                                const float* __restrict__ W,
                                                const float* __restrict__ b,
                                                bf16* __restrict__ Ht,
                                                float* __restrict__ out,
                                                float* __restrict__ lg) {
    __shared__ float Xs[16][260];
    const int t = threadIdx.x;
    const int i0 = blockIdx.x * 16;
    {   // zero out (8 MB) + lg
        const int gt = blockIdx.x * 256 + t;
        const float4 z4 = {0.f, 0.f, 0.f, 0.f};
        float4* o4 = (float4*)out;
        #pragma unroll
        for (int k = 0; k < 4; ++k) o4[gt + k * 128000] = z4;
        if (gt < NN) lg[gt] = 0.f;
    }
    #pragma unroll
    for (int r = 0; r < 16; ++r)
        Xs[r][t] = X[(size_t)(i0 + r) * FD + t];
    __syncthreads();
    const int f = t;
    float acc[16];
    const float bf_ = b[f];
    #pragma unroll
    for (int ii = 0; ii < 16; ++ii) acc[ii] = bf_;
    for (int k4 = 0; k4 < FD / 4; ++k4) {
        const float4 w4 = *(const float4*)&W[(size_t)f * FD + k4 * 4];
        #pragma unroll
        for (int ii = 0; ii < 16; ++ii) {
            const float4 x4 = *(const float4*)&Xs[ii][k4 * 4];
            acc[ii] += x4.x * w4.x + x4.y * w4.y + x4.z * w4.z + x4.w * w4.w;
        }
    }
    bf16x8 v0, v1;
    #pragma unroll
    for (int ii = 0; ii < 8; ++ii) { v0[ii] = (bf16)acc[ii]; v1[ii] = (bf16)acc[ii + 8]; }
    *(bf16x8*)&Ht[(size_t)f * NN + i0]     = v0;
    *(bf16x8*)&Ht[(size_t)f * NN + i0 + 8] = v1;
}

// ---------------- K2: hs = H@a_src + a_b, hd = H@a_dst ----------------
__global__ __launch_bounds__(256) void k_attn_vec(const bf16* __restrict__ Ht,
                                                  const float* __restrict__ a_src,
                                                  const float* __restrict__ a_dst,
                                                  const float* __restrict__ a_b,
                                                  float* __restrict__ hs,
                                                  float* __restrict__ hd) {
    __shared__ float psh[4][64], pdh[4][64];
    const int t = threadIdx.x;
    const int li = t & 63;
    const int q = t >> 6;
    const int i = blockIdx.x * 64 + li;
    float ps = 0.f, pd = 0.f;
    #pragma unroll 8
    for (int fi = 0; fi < 64; ++fi) {
        const int f = q * 64 + fi;
        const float h = (float)Ht[(size_t)f * NN + i];
        ps += h * a_src[f];
        pd += h * a_dst[f];
    }
    psh[q][li] = ps; pdh[q][li] = pd;
    __syncthreads();
    if (q == 0) {
        ps = psh[0][li] + psh[1][li] + psh[2][li] + psh[3][li];
        pd = pdh[0][li] + pdh[1][li] + pdh[2][li] + pdh[3][li];
        hs[i] = ps + a_b[0];
        hd[i] = pd;
    }
}

// ---------------- K3: fused GAT — B from L2, LDS pipe halved ----------------
// Same skeleton as R16 but Bt is GONE: B-frags load global->reg from the
// XCD-local L2-resident Ht slice (jb = bid&3 is constant per XCD). LDS per
// block-step: 92 -> 44 KB. adj keeps DMA triple-buffer; per-iter issue order
// (B first, ad(s+2) after the weight phase) keeps compiler's B-wait at
// vmcnt(1) so ad(s+2) stays in flight (2-step adj lead).
__global__ __launch_bounds__(512, 2) void k_gat(const bf16* __restrict__ Ht,
                                                const int* __restrict__ adj,
                                                const float* __restrict__ hs,
                                                const float* __restrict__ hd,
                                                float* __restrict__ out,
                                                float* __restrict__ lg) {
    __shared__ __attribute__((aligned(16))) int  Adt[3][BM * KT];  // 3 x 8 KB
    __shared__ __attribute__((aligned(16))) bf16 Wt[2][BM * 40];   // 2 x 5 KB (80B rows)
    __shared__ float hd_s[JCH];                                    // 8 KB

    const int t  = threadIdx.x;
    const int l  = t & 63;
    const int wv = t >> 6;
    const int jb = blockIdx.x & 3;
    const int ib = blockIdx.x >> 2;
    const int i0 = ib * BM;
    const int j0 = jb * JCH;
    const int NS = (jb < 3) ? 64 : 58;       // 3*2048 + 1856 = 8000

    // weight mapping: row r (0..63), jslot (0..7) -> 4 j's
    const int r  = t >> 3;
    const int js = t & 7;
    const float hsv = hs[i0 + r];

    // MFMA mapping: wave = (is, fg)
    const int is = wv >> 2, fg = wv & 3;
    const int al = l & 15, asl = l >> 4;

    // B pointers: 4 cf frags, each lane reads its own col's K-slice
    const bf16* bp0 = Ht + (size_t)(fg * 64 +  0 + al) * NN + j0 + asl * 8;
    const bf16* bp1 = bp0 + (size_t)16 * NN;
    const bf16* bp2 = bp0 + (size_t)32 * NN;
    const bf16* bp3 = bp0 + (size_t)48 * NN;

    auto stage_ad = [&](int s_, int buf) {
        const int* src = adj + (size_t)(i0 + r) * NN + j0 + s_ * KT + js * 4;
        int* dst = &Adt[buf][t * 4];    // linear: row r*32 + js*4 == t*4
        __builtin_amdgcn_global_load_lds(
            (const __attribute__((address_space(1))) void*)src,
            (__attribute__((address_space(3))) void*)dst, 16, 0, 0);
    };

    // ---- prologue: hd FIRST (fully drained), then DMA ad(0), ad(1)
    {
        const int jg = j0 + t * 4;
        float4 h4 = {0.f, 0.f, 0.f, 0.f};
        if (jg + 3 < NN) h4 = *(const float4*)(hd + jg);
        *(float4*)&hd_s[t * 4] = h4;
    }
    asm volatile("s_waitcnt vmcnt(0) lgkmcnt(0)" ::: "memory");
    stage_ad(0, 0);
    stage_ad(1, 1);
    __builtin_amdgcn_s_barrier();     // hd_s visible to all waves

    f32x4 acc[2][4];
    #pragma unroll
    for (int rb = 0; rb < 2; ++rb)
        #pragma unroll
        for (int cf = 0; cf < 4; ++cf) acc[rb][cf] = (f32x4){0.f, 0.f, 0.f, 0.f};
    float lsum = 0.f;

    #pragma unroll 1
    for (int s = 0; s < NS; ++s) {
        const int bt = s & 1;

        // 1) issue B(s) loads (L2, register dest) — pinned before weight phase
        const size_t bo = (size_t)s * KT;
        const bf16x8 b0 = *(const bf16x8*)(bp0 + bo);
        const bf16x8 b1 = *(const bf16x8*)(bp1 + bo);
        const bf16x8 b2 = *(const bf16x8*)(bp2 + bo);
        const bf16x8 b3 = *(const bf16x8*)(bp3 + bo);
        __builtin_amdgcn_sched_barrier(0);

        // 2) ensure ad(s) DMA landed (leaves ad(s+1) + B x4 in flight)
        asm volatile("s_waitcnt vmcnt(5)" ::: "memory");

        // 3) weight phase: own 16B of Adt + hd_s; 4 exps -> Wt[bt]
        {
            const int4 a4 = *(const int4*)&Adt[s % 3][t * 4];
            const float4 h4 = *(const float4*)&hd_s[s * KT + js * 4];
            float e, w0, w1, w2, w3;
            e = hsv + h4.x; e = fmaxf(e, NEG_SLOPE * e); w0 = a4.x ? __expf(e) : 0.f;
            e = hsv + h4.y; e = fmaxf(e, NEG_SLOPE * e); w1 = a4.y ? __expf(e) : 0.f;
            e = hsv + h4.z; e = fmaxf(e, NEG_SLOPE * e); w2 = a4.z ? __expf(e) : 0.f;
            e = hsv + h4.w; e = fmaxf(e, NEG_SLOPE * e); w3 = a4.w ? __expf(e) : 0.f;
            lsum += (w0 + w1) + (w2 + w3);
            bf16x4 w4v;
            w4v[0] = (bf16)w0; w4v[1] = (bf16)w1; w4v[2] = (bf16)w2; w4v[3] = (bf16)w3;
            *(bf16x4*)((char*)&Wt[bt][0] + r * 80 + js * 8) = w4v;
        }

        // 4) issue ad(s+2) AFTER B loads -> compiler's B-wait = vmcnt(1)
        if (s + 2 < NS) stage_ad(s + 2, (s + 2) % 3);

        // 5) Wt visible, then barrier (ad(s+2) + B may still fly)
        asm volatile("s_waitcnt lgkmcnt(0)" ::: "memory");
        __builtin_amdgcn_s_barrier();

        // 6) MFMA: A from Wt[bt] (padded rows), B from regs (compiler waits)
        {
            const char* Ab = (const char*)&Wt[bt][0];
            bf16x8 a[2];
            #pragma unroll
            for (int rb = 0; rb < 2; ++rb)
                a[rb] = *(const bf16x8*)(Ab + (is * 32 + rb * 16 + al) * 80 + asl * 16);
            acc[0][0] = __builtin_amdgcn_mfma_f32_16x16x32_bf16(a[0], b0, acc[0][0], 0, 0, 0);
            acc[0][1] = __builtin_amdgcn_mfma_f32_16x16x32_bf16(a[0], b1, acc[0][1], 0, 0, 0);
            acc[0][2] = __builtin_amdgcn_mfma_f32_16x16x32_bf16(a[0], b2, acc[0][2], 0, 0, 0);
            acc[0][3] = __builtin_amdgcn_mfma_f32_16x16x32_bf16(a[0], b3, acc[0][3], 0, 0, 0);
            acc[1][0] = __builtin_amdgcn_mfma_f32_16x16x32_bf16(a[1], b0, acc[1][0], 0, 0, 0);
            acc[1][1] = __builtin_amdgcn_mfma_f32_16x16x32_bf16(a[1], b1, acc[1][1], 0, 0, 0);
            acc[1][2] = __builtin_amdgcn_mfma_f32_16x16x32_bf16(a[1], b2, acc[1][2], 0, 0, 0);
            acc[1][3] = __builtin_amdgcn_mfma_f32_16x16x32_bf16(a[1], b3, acc[1][3], 0, 0, 0);
        }
        asm volatile("s_waitcnt lgkmcnt(0)" ::: "memory");
        __builtin_amdgcn_s_barrier();
    }

    // ---- epilogue: row sums (8 threads share row r) + atomic numerator
    lsum += __shfl_xor(lsum, 1);
    lsum += __shfl_xor(lsum, 2);
    lsum += __shfl_xor(lsum, 4);
    if ((t & 7) == 0) atomicAdd(&lg[i0 + r], lsum);

    #pragma unroll
    for (int rb = 0; rb < 2; ++rb)
        #pragma unroll
        for (int cf = 0; cf < 4; ++cf)
            #pragma unroll
            for (int g = 0; g < 4; ++g)
                atomicAdd(&out[(size_t)(i0 + is * 32 + rb * 16 + asl * 4 + g) * FD
                               + fg * 64 + cf * 16 + al], acc[rb][cf][g]);
}

// ---------------- K4: normalize by row sums ----------------
__global__ __launch_bounds__(256) void k_norm(float* __restrict__ out,
                                              const float* __restrict__ lg) {
    const int i = blockIdx.x;
    const float rinv = 1.0f / lg[i];
    out[(size_t)i * FD + threadIdx.x] *= rinv;
}

extern "C" void kernel_launch(void* const* d_in, const int* in_sizes, int n_in,
                              void* d_out, int out_size, void* d_ws, size_t ws_size,
                              hipStream_t stream) {
    const float* X     = (const float*)d_in[0];
    const int*   adj   = (const int*)d_in[1];
    const float* Ww    = (const float*)d_in[2];
    const float* Wb    = (const float*)d_in[3];
    const float* a_src = (const float*)d_in[4];
    const float* a_dst = (const float*)d_in[5];
    const float* a_b   = (const float*)d_in[6];
    float* out = (float*)d_out;

    bf16*  Ht = (bf16*)d_ws;                                  // 4.096 MB
    float* hs = (float*)((char*)d_ws + (size_t)FD * NN * sizeof(bf16));
    float* hd = hs + NN;
    float* lg = hd + NN;

    k_linear<<<NN / 16, 256, 0, stream>>>(X, Ww, Wb, Ht, out, lg);
    k_attn_vec<<<NN / 64, 256, 0, stream>>>(Ht, a_src, a_dst, a_b, hs, hd);
    k_gat<<<125 * 4, 512, 0, stream>>>(Ht, adj, hs, hd, out, lg);
    k_norm<<<NN, 256, 0, stream>>>(out, lg);
}

// Round 18
// 155.373 us; speedup vs baseline: 1.3573x; 1.3573x over previous
//
#include <hip/hip_runtime.h>

#define NN 8000
#define FD 256
#define NEG_SLOPE 0.2f
#define BM 64                 // i rows per block
#define KT 32                 // j per step
#define JCH 2048              // j chunk (last: 1856)

typedef __bf16 bf16;
typedef __bf16 bf16x8 __attribute__((ext_vector_type(8)));
typedef __bf16 bf16x4 __attribute__((ext_vector_type(4)));
typedef float f32x4 __attribute__((ext_vector_type(4)));

#define MFMA16 __builtin_amdgcn_mfma_f32_16x16x32_bf16
// un-sinkable global load: result pinned in VGPRs at the issue point
#define GLOAD(dst, ptr) \
    asm volatile("global_load_dwordx4 %0, %1, off" : "=v"(dst) : "v"(ptr) : "memory")

// ---------------- K1: H = X @ W^T + b -> Ht (bf16, [f][i]); zero out/lg ----
__global__ __launch_bounds__(256) void k_linear(const float* __restrict__ X,
                                                const float* __restrict__ W,
                                                const float* __restrict__ b,
                                                bf16* __restrict__ Ht,
                                                float* __restrict__ out,
                                                float* __restrict__ lg) {
    __shared__ float Xs[16][260];
    const int t = threadIdx.x;
    const int i0 = blockIdx.x * 16;
    {   // zero out (8 MB) + lg
        const int gt = blockIdx.x * 256 + t;
        const float4 z4 = {0.f, 0.f, 0.f, 0.f};
        float4* o4 = (float4*)out;
        #pragma unroll
        for (int k = 0; k < 4; ++k) o4[gt + k * 128000] = z4;
        if (gt < NN) lg[gt] = 0.f;
    }
    #pragma unroll
    for (int r = 0; r < 16; ++r)
        Xs[r][t] = X[(size_t)(i0 + r) * FD + t];
    __syncthreads();
    const int f = t;
    float acc[16];
    const float bf_ = b[f];
    #pragma unroll
    for (int ii = 0; ii < 16; ++ii) acc[ii] = bf_;
    for (int k4 = 0; k4 < FD / 4; ++k4) {
        const float4 w4 = *(const float4*)&W[(size_t)f * FD + k4 * 4];
        #pragma unroll
        for (int ii = 0; ii < 16; ++ii) {
            const float4 x4 = *(const float4*)&Xs[ii][k4 * 4];
            acc[ii] += x4.x * w4.x + x4.y * w4.y + x4.z * w4.z + x4.w * w4.w;
        }
    }
    bf16x8 v0, v1;
    #pragma unroll
    for (int ii = 0; ii < 8; ++ii) { v0[ii] = (bf16)acc[ii]; v1[ii] = (bf16)acc[ii + 8]; }
    *(bf16x8*)&Ht[(size_t)f * NN + i0]     = v0;
    *(bf16x8*)&Ht[(size_t)f * NN + i0 + 8] = v1;
}

// ---------------- K2: hs = H@a_src + a_b, hd = H@a_dst ----------------
__global__ __launch_bounds__(256) void k_attn_vec(const bf16* __restrict__ Ht,
                                                  const float* __restrict__ a_src,
                                                  const float* __restrict__ a_dst,
                                                  const float* __restrict__ a_b,
                                                  float* __restrict__ hs,
                                                  float* __restrict__ hd) {
    __shared__ float psh[4][64], pdh[4][64];
    const int t = threadIdx.x;
    const int li = t & 63;
    const int q = t >> 6;
    const int i = blockIdx.x * 64 + li;
    float ps = 0.f, pd = 0.f;
    #pragma unroll 8
    for (int fi = 0; fi < 64; ++fi) {
        const int f = q * 64 + fi;
        const float h = (float)Ht[(size_t)f * NN + i];
        ps += h * a_src[f];
        pd += h * a_dst[f];
    }
    psh[q][li] = ps; pdh[q][li] = pd;
    __syncthreads();
    if (q == 0) {
        ps = psh[0][li] + psh[1][li] + psh[2][li] + psh[3][li];
        pd = pdh[0][li] + pdh[1][li] + pdh[2][li] + pdh[3][li];
        hs[i] = ps + a_b[0];
        hd[i] = pd;
    }
}

// ---------------- K3: fused GAT — asm-pinned B prefetch, no duplication ----------------
// 512 thr = 8 waves; wave fg owns 32 UNIQUE f-cols (2 B-frags via inline-asm
// global_load_dwordx4 issued one step ahead — compiler cannot sink them) and
// all 64 rows (4 A-frags from LDS Wt, 8 MFMA). adj via DMA triple-buffer.
// FIFO invariant per iter: issue B(s+1)x2 then ad(s+2); vmcnt(4) completes
// ad(s)+B(s)x2, leaves ad(s+1)+B(s+1)x2+ad(s+2) in flight.
__global__ __launch_bounds__(512, 2) void k_gat(const bf16* __restrict__ Ht,
                                                const int* __restrict__ adj,
                                                const float* __restrict__ hs,
                                                const float* __restrict__ hd,
                                                float* __restrict__ out,
                                                float* __restrict__ lg) {
    __shared__ __attribute__((aligned(16))) int  Adt[3][BM * KT];  // 3 x 8 KB
    __shared__ __attribute__((aligned(16))) bf16 Wt[2][BM * 40];   // 2 x 5 KB (80B rows)
    __shared__ float hd_s[JCH];                                    // 8 KB

    const int t  = threadIdx.x;
    const int l  = t & 63;
    const int fg = t >> 6;                 // wave id: 32 f-cols each
    const int jb = blockIdx.x & 3;
    const int ib = blockIdx.x >> 2;
    const int i0 = ib * BM;
    const int j0 = jb * JCH;
    const int NS = (jb < 3) ? 64 : 58;     // 3*2048 + 1856 = 8000

    // weight mapping: row r (0..63), jslot (0..7) -> 4 j's
    const int r  = t >> 3;
    const int js = t & 7;
    const float hsv = hs[i0 + r];

    // MFMA mapping
    const int al = l & 15, asl = l >> 4;
    const bf16* bpc0 = Ht + (size_t)(fg * 32 + al) * NN + j0 + asl * 8;
    const bf16* bpc1 = bpc0 + (size_t)16 * NN;

    auto stage_ad = [&](int s_, int buf) {
        const int* src = adj + (size_t)(i0 + r) * NN + j0 + s_ * KT + js * 4;
        int* dst = &Adt[buf][t * 4];       // linear: base + lane*16B
        __builtin_amdgcn_global_load_lds(
            (const __attribute__((address_space(1))) void*)src,
            (__attribute__((address_space(3))) void*)dst, 16, 0, 0);
    };

    // ---- prologue: hd staged & drained; then FIFO = ad(0), B(0)x2, ad(1)
    {
        const int jg = j0 + t * 4;
        float4 h4 = {0.f, 0.f, 0.f, 0.f};
        if (jg + 3 < NN) h4 = *(const float4*)(hd + jg);
        *(float4*)&hd_s[t * 4] = h4;
    }
    asm volatile("s_waitcnt vmcnt(0) lgkmcnt(0)" ::: "memory");
    bf16x8 bA0, bA1, bB0, bB1;
    stage_ad(0, 0);
    GLOAD(bA0, bpc0);
    GLOAD(bA1, bpc1);
    stage_ad(1, 1);
    __builtin_amdgcn_s_barrier();          // hd_s visible

    f32x4 acc[4][2];
    #pragma unroll
    for (int rb = 0; rb < 4; ++rb) {
        acc[rb][0] = (f32x4){0.f, 0.f, 0.f, 0.f};
        acc[rb][1] = (f32x4){0.f, 0.f, 0.f, 0.f};
    }
    float lsum = 0.f;

    auto step = [&](int s, bf16x8& u0, bf16x8& u1, bf16x8& f0, bf16x8& f1)
        __attribute__((always_inline)) {
        const int bt = s & 1;
        // 1) issue B(s+1) (asm-pinned), then ad(s+2) DMA
        if (s + 1 < NS) {
            const bf16* p0 = bpc0 + (size_t)(s + 1) * KT;
            const bf16* p1 = bpc1 + (size_t)(s + 1) * KT;
            GLOAD(f0, p0);
            GLOAD(f1, p1);
        }
        if (s + 2 < NS) stage_ad(s + 2, (s + 2) % 3);
        // 2) exact drain: completes ad(s) + B(s)x2
        if (s + 2 < NS)      asm volatile("s_waitcnt vmcnt(4)" ::: "memory");
        else if (s + 1 < NS) asm volatile("s_waitcnt vmcnt(3)" ::: "memory");
        else                 asm volatile("s_waitcnt vmcnt(0)" ::: "memory");

        // 3) weight phase: own 16B of Adt + hd_s; 4 exps -> Wt[bt]
        {
            const int4 a4 = *(const int4*)&Adt[s % 3][t * 4];
            const float4 h4 = *(const float4*)&hd_s[s * KT + js * 4];
            float e, w0, w1, w2, w3;
            e = hsv + h4.x; e = fmaxf(e, NEG_SLOPE * e); w0 = a4.x ? __expf(e) : 0.f;
            e = hsv + h4.y; e = fmaxf(e, NEG_SLOPE * e); w1 = a4.y ? __expf(e) : 0.f;
            e = hsv + h4.z; e = fmaxf(e, NEG_SLOPE * e); w2 = a4.z ? __expf(e) : 0.f;
            e = hsv + h4.w; e = fmaxf(e, NEG_SLOPE * e); w3 = a4.w ? __expf(e) : 0.f;
            lsum += (w0 + w1) + (w2 + w3);
            bf16x4 w4v;
            w4v[0] = (bf16)w0; w4v[1] = (bf16)w1; w4v[2] = (bf16)w2; w4v[3] = (bf16)w3;
            *(bf16x4*)((char*)&Wt[bt][0] + r * 80 + js * 8) = w4v;
        }
        asm volatile("s_waitcnt lgkmcnt(0)" ::: "memory");
        __builtin_amdgcn_s_barrier();

        // 4) MFMA: 4 A-frags (LDS) x 2 B-frags (regs, completed at step 2)
        {
            const char* Ab = (const char*)&Wt[bt][0];
            bf16x8 a;
            #pragma unroll
            for (int rb = 0; rb < 4; ++rb) {
                a = *(const bf16x8*)(Ab + (rb * 16 + al) * 80 + asl * 16);
                acc[rb][0] = MFMA16(a, u0, acc[rb][0], 0, 0, 0);
                acc[rb][1] = MFMA16(a, u1, acc[rb][1], 0, 0, 0);
            }
        }
        asm volatile("s_waitcnt lgkmcnt(0)" ::: "memory");
        __builtin_amdgcn_s_barrier();
    };

    #pragma unroll 1
    for (int s2 = 0; s2 < NS; s2 += 2) {   // NS is even (64 or 58)
        step(s2,     bA0, bA1, bB0, bB1);
        step(s2 + 1, bB0, bB1, bA0, bA1);
    }

    // ---- epilogue: row sums (8 threads share row r) + atomic numerator
    lsum += __shfl_xor(lsum, 1);
    lsum += __shfl_xor(lsum, 2);
    lsum += __shfl_xor(lsum, 4);
    if ((t & 7) == 0) atomicAdd(&lg[i0 + r], lsum);

    #pragma unroll
    for (int rb = 0; rb < 4; ++rb)
        #pragma unroll
        for (int cf = 0; cf < 2; ++cf)
            #pragma unroll
            for (int g = 0; g < 4; ++g)
                atomicAdd(&out[(size_t)(i0 + rb * 16 + asl * 4 + g) * FD
                               + fg * 32 + cf * 16 + al], acc[rb][cf][g]);
}

// ---------------- K4: normalize by row sums ----------------
__global__ __launch_bounds__(256) void k_norm(float* __restrict__ out,
                                              const float* __restrict__ lg) {
    const int i = blockIdx.x;
    const float rinv = 1.0f / lg[i];
    out[(size_t)i * FD + threadIdx.x] *= rinv;
}

extern "C" void kernel_launch(void* const* d_in, const int* in_sizes, int n_in,
                              void* d_out, int out_size, void* d_ws, size_t ws_size,
                              hipStream_t stream) {
    const float* X     = (const float*)d_in[0];
    const int*   adj   = (const int*)d_in[1];
    const float* Ww    = (const float*)d_in[2];
    const float* Wb    = (const float*)d_in[3];
    const float* a_src = (const float*)d_in[4];
    const float* a_dst = (const float*)d_in[5];
    const float* a_b   = (const float*)d_in[6];
    float* out = (float*)d_out;

    bf16*  Ht = (bf16*)d_ws;                                  // 4.096 MB
    float* hs = (float*)((char*)d_ws + (size_t)FD * NN * sizeof(bf16));
    float* hd = hs + NN;
    float* lg = hd + NN;

    k_linear<<<NN / 16, 256, 0, stream>>>(X, Ww, Wb, Ht, out, lg);
    k_attn_vec<<<NN / 64, 256, 0, stream>>>(Ht, a_src, a_dst, a_b, hs, hd);
    k_gat<<<125 * 4, 512, 0, stream>>>(Ht, adj, hs, hd, out, lg);
    k_norm<<<NN, 256, 0, stream>>>(out, lg);
}

// Round 19
// 151.426 us; speedup vs baseline: 1.3926x; 1.0261x over previous
//
#include <hip/hip_runtime.h>

#define NN 8000
#define FD 256
#define NEG_SLOPE 0.2f
#define BM 128                // i rows per block (tail block clamps)
#define KT 32                 // j per step
#define NJB 8                 // j chunks of 1024 (last: 832)
#define JCH 1024

typedef __bf16 bf16;
typedef __bf16 bf16x8 __attribute__((ext_vector_type(8)));
typedef float f32x4 __attribute__((ext_vector_type(4)));

#define MFMA16 __builtin_amdgcn_mfma_f32_16x16x32_bf16

// ---------------- K1: H = X @ W^T + b -> Ht (bf16, [f][i]) ----------------
__global__ __launch_bounds__(256) void k_linear(const float* __restrict__ X,
                                                const float* __restrict__ W,
                                                const float* __restrict__ b,
                                                bf16* __restrict__ Ht) {
    __shared__ float Xs[16][260];
    const int t = threadIdx.x;
    const int i0 = blockIdx.x * 16;
    #pragma unroll
    for (int r = 0; r < 16; ++r)
        Xs[r][t] = X[(size_t)(i0 + r) * FD + t];
    __syncthreads();
    const int f = t;
    float acc[16];
    const float bf_ = b[f];
    #pragma unroll
    for (int ii = 0; ii < 16; ++ii) acc[ii] = bf_;
    for (int k4 = 0; k4 < FD / 4; ++k4) {
        const float4 w4 = *(const float4*)&W[(size_t)f * FD + k4 * 4];
        #pragma unroll
        for (int ii = 0; ii < 16; ++ii) {
            const float4 x4 = *(const float4*)&Xs[ii][k4 * 4];
            acc[ii] += x4.x * w4.x + x4.y * w4.y + x4.z * w4.z + x4.w * w4.w;
        }
    }
    bf16x8 v0, v1;
    #pragma unroll
    for (int ii = 0; ii < 8; ++ii) { v0[ii] = (bf16)acc[ii]; v1[ii] = (bf16)acc[ii + 8]; }
    *(bf16x8*)&Ht[(size_t)f * NN + i0]     = v0;
    *(bf16x8*)&Ht[(size_t)f * NN + i0 + 8] = v1;
}

// ---------------- K2: hs = H@a_src + a_b, hd = H@a_dst ----------------
__global__ __launch_bounds__(256) void k_attn_vec(const bf16* __restrict__ Ht,
                                                  const float* __restrict__ a_src,
                                                  const float* __restrict__ a_dst,
                                                  const float* __restrict__ a_b,
                                                  float* __restrict__ hs,
                                                  float* __restrict__ hd) {
    __shared__ float psh[4][64], pdh[4][64];
    const int t = threadIdx.x;
    const int li = t & 63;
    const int q = t >> 6;
    const int i = blockIdx.x * 64 + li;
    float ps = 0.f, pd = 0.f;
    #pragma unroll 8
    for (int fi = 0; fi < 64; ++fi) {
        const int f = q * 64 + fi;
        const float h = (float)Ht[(size_t)f * NN + i];
        ps += h * a_src[f];
        pd += h * a_dst[f];
    }
    psh[q][li] = ps; pdh[q][li] = pd;
    __syncthreads();
    if (q == 0) {
        ps = psh[0][li] + psh[1][li] + psh[2][li] + psh[3][li];
        pd = pdh[0][li] + pdh[1][li] + pdh[2][li] + pdh[3][li];
        hs[i] = ps + a_b[0];
        hd[i] = pd;
    }
}

// ---------------- K3: big-tile fused GAT (128i x 256f x 32k per step) ----------------
// 512 thr = 8 waves (2 row-halves x 4 col-groups); each wave owns 64x64 output
// (acc 4x4) -> 16 MFMA per 8 ds_read_b128 (2:1, frags reused 4x). 1M MACs per
// block-step amortizes the fixed step overhead that capped R7-R18 at ~150us.
// adj: self-staged DMA 2-deep (thread reads back its own 32B -> no barrier
// before weight phase). Bt slot-XOR both sides. Wt 72B rows (<=2-way banks).
// No atomics: per-jb partials (unique writers), combined in k_norm.
__global__ __launch_bounds__(512, 4) void k_gat(const bf16* __restrict__ Ht,
                                                const int* __restrict__ adj,
                                                const float* __restrict__ hs,
                                                const float* __restrict__ hd,
                                                float* __restrict__ outP,
                                                float* __restrict__ lgP) {
    __shared__ __attribute__((aligned(16))) bf16 Bt[2][FD * KT];   // 2 x 16 KB
    __shared__ __attribute__((aligned(16))) int  Adt[2][BM * KT];  // 2 x 16 KB
    __shared__ __attribute__((aligned(16))) char Wt[BM * 72];      // 9 KB
    __shared__ float hd_s[JCH];                                    // 4 KB  (77.25 KB tot)

    const int t  = threadIdx.x;
    const int l  = t & 63;
    const int wv = t >> 6;
    const int jb = blockIdx.x & 7;
    const int ib = blockIdx.x >> 3;          // 0..62 (ib=62: rows 7936..8063, clamped)
    const int i0 = ib * BM;
    const int j0 = jb * JCH;
    const int NS = (jb < 7) ? 32 : 26;       // 7*1024 + 832 = 8000

    // weight mapping: row r (0..127, 4 thr/row), 8 j's at (t&3)*8
    const int r   = t >> 2;
    const int js4 = t & 3;
    const int ig  = min(i0 + r, NN - 1);     // tail clamp
    const float hsv = hs[ig];

    // MFMA mapping
    const int al = l & 15, asl = l >> 4;
    const int wr = wv >> 2, wc = wv & 3;

    auto stage_ad = [&](int s_, int buf) {   // self-staged: dest t*16 == own read
        const int* src = adj + (size_t)ig * NN + j0 + s_ * KT + js4 * 8;
        __builtin_amdgcn_global_load_lds(
            (const __attribute__((address_space(1))) void*)src,
            (__attribute__((address_space(3))) void*)&Adt[buf][t * 4], 16, 0, 0);
        __builtin_amdgcn_global_load_lds(
            (const __attribute__((address_space(1))) void*)(src + 4),
            (__attribute__((address_space(3))) void*)&Adt[buf][2048 + t * 4], 16, 0, 0);
    };
    auto stage_bt = [&](int s_, int buf) {
        #pragma unroll
        for (int q = 0; q < 2; ++q) {
            const int idx = q * 512 + t;
            const int f = idx >> 2, sl = idx & 3;
            const int ss = sl ^ ((f >> 2) & 3);
            const bf16* src = Ht + (size_t)f * NN + j0 + s_ * KT + ss * 8;
            __builtin_amdgcn_global_load_lds(
                (const __attribute__((address_space(1))) void*)src,
                (__attribute__((address_space(3))) void*)&Bt[buf][idx * 8], 16, 0, 0);
        }
    };

    // ---- prologue: hd_s staged & drained; then DMA ad(0), bt(0)
    {
        const int jg = j0 + t * 2;
        float2 h2 = {0.f, 0.f};
        if (jg + 1 < NN) h2 = *(const float2*)(hd + jg);
        *(float2*)&hd_s[t * 2] = h2;
    }
    asm volatile("s_waitcnt vmcnt(0) lgkmcnt(0)" ::: "memory");
    stage_ad(0, 0);
    stage_bt(0, 0);
    __builtin_amdgcn_s_barrier();            // hd_s visible

    f32x4 acc[4][4];
    #pragma unroll
    for (int rb = 0; rb < 4; ++rb)
        #pragma unroll
        for (int cf = 0; cf < 4; ++cf) acc[rb][cf] = (f32x4){0.f, 0.f, 0.f, 0.f};
    float lsum = 0.f;

    #pragma unroll 1
    for (int s = 0; s < NS; ++s) {
        const int buf = s & 1;
        // 1) issue next step's 4 DMAs
        if (s + 1 < NS) { stage_ad(s + 1, buf ^ 1); stage_bt(s + 1, buf ^ 1); }
        // 2) drain ad(s)+bt(s); leave next step's 4 in flight
        if (s + 1 < NS) asm volatile("s_waitcnt vmcnt(4)" ::: "memory");
        else            asm volatile("s_waitcnt vmcnt(0)" ::: "memory");

        // 3) weight phase: 8 w's from own Adt bytes + hd_s broadcast
        {
            const int4 alo = *(const int4*)&Adt[buf][t * 4];
            const int4 ahi = *(const int4*)&Adt[buf][2048 + t * 4];
            const float4 hlo = *(const float4*)&hd_s[s * KT + js4 * 8];
            const float4 hhi = *(const float4*)&hd_s[s * KT + js4 * 8 + 4];
            float e, w0, w1, w2, w3, w4, w5, w6, w7;
            e = hsv + hlo.x; e = fmaxf(e, NEG_SLOPE * e); w0 = alo.x ? __expf(e) : 0.f;
            e = hsv + hlo.y; e = fmaxf(e, NEG_SLOPE * e); w1 = alo.y ? __expf(e) : 0.f;
            e = hsv + hlo.z; e = fmaxf(e, NEG_SLOPE * e); w2 = alo.z ? __expf(e) : 0.f;
            e = hsv + hlo.w; e = fmaxf(e, NEG_SLOPE * e); w3 = alo.w ? __expf(e) : 0.f;
            e = hsv + hhi.x; e = fmaxf(e, NEG_SLOPE * e); w4 = ahi.x ? __expf(e) : 0.f;
            e = hsv + hhi.y; e = fmaxf(e, NEG_SLOPE * e); w5 = ahi.y ? __expf(e) : 0.f;
            e = hsv + hhi.z; e = fmaxf(e, NEG_SLOPE * e); w6 = ahi.z ? __expf(e) : 0.f;
            e = hsv + hhi.w; e = fmaxf(e, NEG_SLOPE * e); w7 = ahi.w ? __expf(e) : 0.f;
            lsum += ((w0 + w1) + (w2 + w3)) + ((w4 + w5) + (w6 + w7));
            bf16x8 w8;
            w8[0] = (bf16)w0; w8[1] = (bf16)w1; w8[2] = (bf16)w2; w8[3] = (bf16)w3;
            w8[4] = (bf16)w4; w8[5] = (bf16)w5; w8[6] = (bf16)w6; w8[7] = (bf16)w7;
            *(bf16x8*)(Wt + r * 72 + js4 * 16) = w8;
        }
        asm volatile("s_waitcnt lgkmcnt(0)" ::: "memory");
        __builtin_amdgcn_s_barrier();        // Wt + Bt[buf] ready

        // 4) MFMA: 4 B-frags preloaded, A-frag streamed (2:1 MFMA:ds_read)
        {
            bf16x8 b[4];
            #pragma unroll
            for (int cf = 0; cf < 4; ++cf) {
                const int f = wc * 64 + cf * 16 + al;
                b[cf] = *(const bf16x8*)((const char*)&Bt[buf][0] + f * 64
                                         + ((asl ^ ((f >> 2) & 3)) << 4));
            }
            #pragma unroll
            for (int rb = 0; rb < 4; ++rb) {
                const bf16x8 a = *(const bf16x8*)(Wt + (wr * 64 + rb * 16 + al) * 72
                                                  + asl * 16);
                acc[rb][0] = MFMA16(a, b[0], acc[rb][0], 0, 0, 0);
                acc[rb][1] = MFMA16(a, b[1], acc[rb][1], 0, 0, 0);
                acc[rb][2] = MFMA16(a, b[2], acc[rb][2], 0, 0, 0);
                acc[rb][3] = MFMA16(a, b[3], acc[rb][3], 0, 0, 0);
            }
        }
        asm volatile("s_waitcnt lgkmcnt(0)" ::: "memory");
        __builtin_amdgcn_s_barrier();        // all reads done before overwrite
    }

    // ---- epilogue: per-jb row sums (4 thr/row reduce) + partial stores
    lsum += __shfl_xor(lsum, 1);
    lsum += __shfl_xor(lsum, 2);
    if (js4 == 0 && i0 + r < NN) lgP[(size_t)jb * NN + i0 + r] = lsum;

    float* op = outP + (size_t)jb * NN * FD;
    #pragma unroll
    for (int rb = 0; rb < 4; ++rb) {
        #pragma unroll
        for (int g = 0; g < 4; ++g) {
            const int i = i0 + wr * 64 + rb * 16 + asl * 4 + g;
            if (i < NN) {
                float* orow = op + (size_t)i * FD + wc * 64 + al;
                orow[0]  = acc[rb][0][g];
                orow[16] = acc[rb][1][g];
                orow[32] = acc[rb][2][g];
                orow[48] = acc[rb][3][g];
            }
        }
    }
}

// ---------------- K4: combine 8 partials + normalize ----------------
__global__ __launch_bounds__(256) void k_norm(const float* __restrict__ outP,
                                              const float* __restrict__ lgP,
                                              float* __restrict__ out) {
    const int i = blockIdx.x;
    const int f = threadIdx.x;
    float ls = 0.f;
    #pragma unroll
    for (int c = 0; c < NJB; ++c) ls += lgP[(size_t)c * NN + i];
    float v = 0.f;
    #pragma unroll
    for (int c = 0; c < NJB; ++c) v += outP[(size_t)c * NN * FD + (size_t)i * FD + f];
    out[(size_t)i * FD + f] = v * (1.0f / ls);
}

extern "C" void kernel_launch(void* const* d_in, const int* in_sizes, int n_in,
                              void* d_out, int out_size, void* d_ws, size_t ws_size,
                              hipStream_t stream) {
    const float* X     = (const float*)d_in[0];
    const int*   adj   = (const int*)d_in[1];
    const float* Ww    = (const float*)d_in[2];
    const float* Wb    = (const float*)d_in[3];
    const float* a_src = (const float*)d_in[4];
    const float* a_dst = (const float*)d_in[5];
    const float* a_b   = (const float*)d_in[6];
    float* out = (float*)d_out;

    bf16*  Ht   = (bf16*)d_ws;                                // 4.096 MB
    float* hs   = (float*)((char*)d_ws + (size_t)FD * NN * sizeof(bf16));
    float* hd   = hs + NN;
    float* lgP  = hd + NN;                                    // 8*NN f32
    float* outP = lgP + (size_t)NJB * NN;                     // 8*NN*FD f32 = 65.5 MB

    k_linear<<<NN / 16, 256, 0, stream>>>(X, Ww, Wb, Ht);
    k_attn_vec<<<NN / 64, 256, 0, stream>>>(Ht, a_src, a_dst, a_b, hs, hd);
    k_gat<<<63 * NJB, 512, 0, stream>>>(Ht, adj, hs, hd, outP, lgP);
    k_norm<<<NN, 256, 0, stream>>>(outP, lgP, out);
}